// Round 3
// baseline (181.325 us; speedup 1.0000x reference)
//
#include <hip/hip_runtime.h>
#include <hip/hip_bf16.h>

// SNN spike layer: causal alpha-PSP conv (K<=77) + sequential refractory scan.
// One thread per neuron; time in 15 chunks of 20; register-resident 97-entry
// spike history window; 20 independent FMA chains for ILP at 1 wave/SIMD.
//
// R3: __attribute__((amdgpu_waves_per_eu(1,1))). R1/R2 showed the allocator
// pinned VGPRs at 96 (spilling ~164 floats/thread to scratch: WRITE_SIZE
// 121 MB vs 78.6 MB compulsory, VALUBusy 58%) and __launch_bounds__(256,1)
// did NOT lift the cap. The grid is 1024 waves = exactly 1 wave/SIMD
// chip-wide, so occupancy is grid-bound: allowing 512 VGPR/wave is free.
// Also: pend shift merged into FMA (bit-exact for s in {0,1}), so[] folded
// into u[] (-20 live VGPRs, -2.3us of movs).

#define T_LEN 300
#define CH 20
#define NCHUNK 15          // 15 * 20 == 300 exactly
#define KS 77              // srm kernel length (alpha, tau=10, eps_tol=0.01)
#define KR 10              // ref kernel tail length (K_ref=11 -> 10 pending slots)
#define THETA_V 10.0f

__global__ __launch_bounds__(256)
__attribute__((amdgpu_waves_per_eu(1, 1)))
void spike_layer_kernel(
    const float* __restrict__ spike_in,
    const float* __restrict__ srm, int srm_len,
    const float* __restrict__ refk, int ref_len,
    float* __restrict__ out, int B)
{
    int b = blockIdx.x * blockDim.x + threadIdx.x;
    if (b >= B) return;

    const float* row  = spike_in + (size_t)b * T_LEN;
    float*       orow = out      + (size_t)b * T_LEN;

    // srm taps: wave-uniform -> compiler scalarizes into SGPRs
    float srm_r[KS];
#pragma unroll
    for (int i = 0; i < KS; ++i) srm_r[i] = (i < srm_len) ? srm[i] : 0.0f;

    // refractory tail: ref_kernel[1..], contributions to t+1..t+KR
    float rt[KR];
#pragma unroll
    for (int i = 0; i < KR; ++i) rt[i] = (i + 1 < ref_len) ? refk[i + 1] : 0.0f;

    // history window: hist[i] = s[t0 + i - KS]; hist[KS..KS+CH-1] = current chunk
    float hist[KS + CH];
#pragma unroll
    for (int i = 0; i < KS; ++i) hist[i] = 0.0f;   // t < 0 -> no spikes

    float pend[KR];
#pragma unroll
    for (int i = 0; i < KR; ++i) pend[i] = 0.0f;

    // preload chunk 0
    float nxt[CH];
    {
        const float4* p = (const float4*)row;
#pragma unroll
        for (int i = 0; i < CH / 4; ++i) {
            float4 v = p[i];
            nxt[4*i+0] = v.x; nxt[4*i+1] = v.y; nxt[4*i+2] = v.z; nxt[4*i+3] = v.w;
        }
    }

#pragma unroll 1           // keep the ~2k-inst body I-cache resident
    for (int ch = 0; ch < NCHUNK; ++ch) {
        // install current chunk into window tail
#pragma unroll
        for (int i = 0; i < CH; ++i) hist[KS + i] = nxt[i];

        // prefetch next chunk (hidden under the 1540-FMA conv below)
        if (ch + 1 < NCHUNK) {
            const float4* p = (const float4*)(row + (ch + 1) * CH);
#pragma unroll
            for (int i = 0; i < CH / 4; ++i) {
                float4 v = p[i];
                nxt[4*i+0] = v.x; nxt[4*i+1] = v.y; nxt[4*i+2] = v.z; nxt[4*i+3] = v.w;
            }
        }

        // conv: u[t0+c] = sum_j srm[j] * s[t0+c-j]; 20 independent chains
        float u[CH];
#pragma unroll
        for (int c = 0; c < CH; ++c) u[c] = 0.0f;
#pragma unroll
        for (int j = 0; j < KS; ++j) {
            float w = srm_r[j];
#pragma unroll
            for (int c = 0; c < CH; ++c)
                u[c] = fmaf(w, hist[KS + c - j], u[c]);
        }

        // sequential threshold scan; shift fused into FMA (exact: s in {0,1})
#pragma unroll
        for (int c = 0; c < CH; ++c) {
            float u_eff = u[c] + pend[0];
            float s = (u_eff >= THETA_V) ? 1.0f : 0.0f;
#pragma unroll
            for (int i = 0; i < KR - 1; ++i) pend[i] = fmaf(s, rt[i], pend[i + 1]);
            pend[KR - 1] = s * rt[KR - 1];
            u[c] = s;      // reuse u[] as the output buffer (s / TS, TS == 1)
        }

        // store chunk
        {
            float4* op = (float4*)(orow + ch * CH);
#pragma unroll
            for (int i = 0; i < CH / 4; ++i) {
                float4 v;
                v.x = u[4*i+0]; v.y = u[4*i+1]; v.z = u[4*i+2]; v.w = u[4*i+3];
                op[i] = v;
            }
        }

        // slide window by CH
#pragma unroll
        for (int i = 0; i < KS; ++i) hist[i] = hist[i + CH];
    }
}

extern "C" void kernel_launch(void* const* d_in, const int* in_sizes, int n_in,
                              void* d_out, int out_size, void* d_ws, size_t ws_size,
                              hipStream_t stream) {
    const float* spike_in = (const float*)d_in[0];
    const float* srm      = (const float*)d_in[1];
    const float* refk     = (const float*)d_in[2];
    float* out = (float*)d_out;

    int srm_len = in_sizes[1];
    int ref_len = in_sizes[2];
    int B = in_sizes[0] / T_LEN;   // 65536 neurons

    int block = 256;
    int grid = (B + block - 1) / block;
    spike_layer_kernel<<<grid, block, 0, stream>>>(spike_in, srm, srm_len,
                                                   refk, ref_len, out, B);
}

// Round 4
// 180.358 us; speedup vs baseline: 1.0054x; 1.0054x over previous
//
#include <hip/hip_runtime.h>
#include <hip/hip_bf16.h>

// SNN spike layer: causal alpha-PSP conv (K<=77) + sequential refractory scan.
// One thread per neuron; time in 15 chunks of 20.
//
// R4: the 97-entry spike-history window lives in LDS (column layout
// hist[i][tid] -> lane L hits bank L%32, 2 lanes/bank = conflict-free,
// free per m136), NOT in registers. R1-R3 showed the compiler scratch-homes
// the big per-thread array regardless of launch-bounds hints (WRITE_SIZE
// 121 MB vs 78.6 compulsory, VALUBusy 57%). 97*256*4 = 99.3 KB/block forces
// 1 block/CU == exactly our grid (256 blocks on 256 CUs): zero occupancy
// cost. Each thread touches only its own column -> NO barriers.
// Current-chunk spikes are read from the nxt prefetch registers (window
// i>=77), so LDS ops/chunk ~= 208 vs 1540 FMAs -> LDS pipe stays hidden
// under VALU.

#define T_LEN 300
#define CH 20
#define NCHUNK 15          // 15 * 20 == 300 exactly
#define KS 77              // srm kernel length (alpha, tau=10, eps_tol=0.01)
#define KR 10              // ref kernel tail (K_ref=11 -> 10 pending slots)
#define THETA_V 10.0f
#define NTH 256
#define WIN 97             // window slots [0..96]; conv reads [1..96]

__global__ __launch_bounds__(NTH)
__attribute__((amdgpu_waves_per_eu(1, 1)))
void spike_layer_kernel(
    const float* __restrict__ spike_in,
    const float* __restrict__ srm, int srm_len,
    const float* __restrict__ refk, int ref_len,
    float* __restrict__ out, int B)
{
    __shared__ float hist[WIN * NTH];   // 99,328 B -> 1 block/CU

    const int tid = threadIdx.x;
    int b = blockIdx.x * NTH + tid;
    if (b >= B) return;                 // no barriers in kernel: early-out safe

    const float* row  = spike_in + (size_t)b * T_LEN;
    float*       orow = out      + (size_t)b * T_LEN;

    // srm taps: wave-uniform loads + constant indices -> SGPRs
    float srm_r[KS];
#pragma unroll
    for (int i = 0; i < KS; ++i) srm_r[i] = (i < srm_len) ? srm[i] : 0.0f;

    // refractory tail: ref_kernel[1..], contributions to t+1..t+KR
    float rt[KR];
#pragma unroll
    for (int i = 0; i < KR; ++i) rt[i] = (i + 1 < ref_len) ? refk[i + 1] : 0.0f;

    // zero pre-history (slots 1..76 are read by chunk 0's conv)
#pragma unroll
    for (int i = 0; i < WIN; ++i) hist[i * NTH + tid] = 0.0f;

    float pend[KR];
#pragma unroll
    for (int i = 0; i < KR; ++i) pend[i] = 0.0f;

    // preload chunk 0 into registers
    float nxt[CH];
    {
        const float4* p = (const float4*)row;
#pragma unroll
        for (int i = 0; i < CH / 4; ++i) {
            float4 v = p[i];
            nxt[4*i+0] = v.x; nxt[4*i+1] = v.y; nxt[4*i+2] = v.z; nxt[4*i+3] = v.w;
        }
    }

#pragma unroll 1           // ~1.9k-inst body: keep I-cache resident
    for (int ch = 0; ch < NCHUNK; ++ch) {
        // conv: u[c] = sum_j srm[j] * s[t0+c-j].
        // Window slot i corresponds to j = KS + c - i; slots [1..76] come
        // from LDS history, slots [77..96] are the current chunk in nxt[].
        float u[CH];
#pragma unroll
        for (int c = 0; c < CH; ++c) u[c] = 0.0f;

#pragma unroll
        for (int i = 1; i < WIN + CH; ++i) {
            if (i >= WIN && i - KS >= CH) break;      // folded at compile time
            float h = (i < KS) ? hist[i * NTH + tid] : nxt[i - KS];
            const int clo = (i - KS < 0) ? 0 : i - KS;
            const int chi = (i - 1 < CH - 1) ? i - 1 : CH - 1;
#pragma unroll
            for (int c = clo; c <= chi; ++c)
                u[c] = fmaf(srm_r[c + KS - i], h, u[c]);
        }

        // slide window by CH: slots [1..56] <- [21..76], [57..76] <- nxt
#pragma unroll
        for (int i = 1; i < KS - CH; ++i)
            hist[i * NTH + tid] = hist[(i + CH) * NTH + tid];
#pragma unroll
        for (int i = KS - CH; i < KS; ++i)
            hist[i * NTH + tid] = nxt[i - (KS - CH)];

        // prefetch next chunk (latency hidden under scan + next conv)
        if (ch + 1 < NCHUNK) {
            const float4* p = (const float4*)(row + (ch + 1) * CH);
#pragma unroll
            for (int i = 0; i < CH / 4; ++i) {
                float4 v = p[i];
                nxt[4*i+0] = v.x; nxt[4*i+1] = v.y; nxt[4*i+2] = v.z; nxt[4*i+3] = v.w;
            }
        }

        // sequential threshold scan; shift fused into FMA (exact: s in {0,1})
#pragma unroll
        for (int c = 0; c < CH; ++c) {
            float u_eff = u[c] + pend[0];
            float s = (u_eff >= THETA_V) ? 1.0f : 0.0f;
#pragma unroll
            for (int i = 0; i < KR - 1; ++i) pend[i] = fmaf(s, rt[i], pend[i + 1]);
            pend[KR - 1] = s * rt[KR - 1];
            u[c] = s;      // reuse u[] as output buffer (s / TS, TS == 1)
        }

        // store chunk
        {
            float4* op = (float4*)(orow + ch * CH);
#pragma unroll
            for (int i = 0; i < CH / 4; ++i) {
                float4 v;
                v.x = u[4*i+0]; v.y = u[4*i+1]; v.z = u[4*i+2]; v.w = u[4*i+3];
                op[i] = v;
            }
        }
    }
}

extern "C" void kernel_launch(void* const* d_in, const int* in_sizes, int n_in,
                              void* d_out, int out_size, void* d_ws, size_t ws_size,
                              hipStream_t stream) {
    const float* spike_in = (const float*)d_in[0];
    const float* srm      = (const float*)d_in[1];
    const float* refk     = (const float*)d_in[2];
    float* out = (float*)d_out;

    int srm_len = in_sizes[1];
    int ref_len = in_sizes[2];
    int B = in_sizes[0] / T_LEN;   // 65536 neurons

    int block = NTH;
    int grid = (B + block - 1) / block;   // 256 blocks -> 1 per CU
    spike_layer_kernel<<<grid, block, 0, stream>>>(spike_in, srm, srm_len,
                                                   refk, ref_len, out, B);
}